// Round 7
// baseline (318.029 us; speedup 1.0000x reference)
//
#include <hip/hip_runtime.h>
#include <hip/hip_bf16.h>
#include <math.h>
#include <stdint.h>

#define NB 128     // batch (images and captions)
#define NR 36      // regions
#define NW 64      // words
#define ND 1024    // dim
#define MT 48      // NR padded to 3 MFMA m-tiles
#define EPSF 1e-8f
#define LAM_SM 9.0f
#define LAM_LSE 6.0f
#define MARGINF 0.2f

typedef _Float16 f16;
typedef f16 f16x4 __attribute__((ext_vector_type(4)));
typedef f16 f16x8 __attribute__((ext_vector_type(8)));
typedef float f32x4 __attribute__((ext_vector_type(4)));

__device__ __forceinline__ void gld_lds16(const void* g, void* l) {
    __builtin_amdgcn_global_load_lds(
        (const __attribute__((address_space(1))) uint32_t*)(uintptr_t)g,
        (__attribute__((address_space(3))) uint32_t*)(uint32_t)(uintptr_t)l,
        16, 0, 0);
}

// ---------------- kernel 0: fp32 -> f16 (im zero-padded to 48 rows) + ncap --------
__global__ __launch_bounds__(256) void convert_kernel(
    const float* __restrict__ im, const float* __restrict__ s,
    f16* __restrict__ im48, f16* __restrict__ s16, float* __restrict__ ncap) {
    __shared__ float wsum[4];
    const int b = blockIdx.x, row = blockIdx.y, t = threadIdx.x;
    if (row < MT) {
        f16x4* dst = (f16x4*)(im48 + ((size_t)b * MT + row) * ND);
        if (row < NR) {
            const float4* src = (const float4*)(im + ((size_t)b * NR + row) * ND);
            float4 v = src[t];
            f16x4 h = {(f16)v.x, (f16)v.y, (f16)v.z, (f16)v.w};
            dst[t] = h;
        } else {
            dst[t] = (f16x4){(f16)0.f, (f16)0.f, (f16)0.f, (f16)0.f};
        }
    } else {
        const int w = row - MT;
        const float4* src = (const float4*)(s + ((size_t)b * NW + w) * ND);
        float4 v = src[t];
        f16x4 h = {(f16)v.x, (f16)v.y, (f16)v.z, (f16)v.w};
        ((f16x4*)(s16 + ((size_t)b * NW + w) * ND))[t] = h;
        float ss = v.x * v.x + v.y * v.y + v.z * v.z + v.w * v.w;
        #pragma unroll
        for (int off = 1; off < 64; off <<= 1) ss += __shfl_xor(ss, off, 64);
        if ((t & 63) == 0) wsum[t >> 6] = ss;
        __syncthreads();
        if (t == 0) ncap[b * NW + w] = sqrtf(wsum[0] + wsum[1] + wsum[2] + wsum[3]);
    }
}

// ---------------- kernel A: per-image f16 Gram [48][64] via MFMA ------------------
__global__ __launch_bounds__(256) void gram16_kernel(
    const f16* __restrict__ im48, f16* __restrict__ Mg16) {
    const int b = blockIdx.x, mt = blockIdx.y;          // mt 0..2
    const int wave = threadIdx.x >> 6, lane = threadIdx.x & 63;
    const int quad = lane >> 4, l16 = lane & 15;
    const int nt = wave;                                 // n-tile 0..3
    const f16* Ab = im48 + (size_t)b * (MT * ND);
    f32x4 acc = (f32x4){0.f, 0.f, 0.f, 0.f};
    for (int kk = 0; kk < ND; kk += 32) {
        f16x8 af = *(const f16x8*)(Ab + (mt * 16 + l16) * ND + kk + quad * 8);
        f16x8 bf = *(const f16x8*)(Ab + (nt * 16 + l16) * ND + kk + quad * 8);
        acc = __builtin_amdgcn_mfma_f32_16x16x32_f16(af, bf, acc, 0, 0, 0);
    }
    f16* Mb = Mg16 + (size_t)b * (MT * NW);
    #pragma unroll
    for (int r = 0; r < 4; ++r) {
        int row = mt * 16 + quad * 4 + r;
        Mb[row * NW + nt * 16 + l16] = (f16)acc[r];
    }
}

// ---------------- kernel B: fused GEMM + epilogue -----------------------------
// Block tile 96x128 = 2 images (48 rows each) x 2 captions (64 cols each).
// Wave = (image, caption): acc[3][4] = one full pair -> wave-private epilogue.
// R6-proven staging: 128B LDS rows, exact XOR swizzle (0 conflicts), gld_lds16.
// eT scratch (4 x 8KB) overlays dead staging LDS after the K-loop.
#define A_LDS 12288   // 96 rows x 128 B
__global__ __launch_bounds__(256) void fused_pair_kernel(
    const f16* __restrict__ im48, const f16* __restrict__ s16,
    const int* __restrict__ s_l, const f16* __restrict__ Mg16,
    const float* __restrict__ ncap, float* __restrict__ scores) {
    __shared__ __align__(16) char lds[32768];
    char* As = lds;              // [96][128B]
    char* Bs = lds + A_LDS;      // [128][128B]
    const int t = threadIdx.x;
    const int wave = t >> 6, lane = t & 63;
    const int quad = lane >> 4, l16 = lane & 15;
    const int wi = wave >> 1, wj = wave & 1;

    // XCD-aware: XCD x owns gx in [8x, 8x+8) (2MB of B, L2-hot); gy fast.
    const int lin = blockIdx.x;            // 0..4095
    const int xcd = lin & 7, k = lin >> 3; // 0..511
    const int gy = k & 63, gx = xcd * 8 + (k >> 6);
    const int i = gy * 2 + wi;             // this wave's image
    const int j = gx * 2 + wj;             // this wave's caption
    const int L = s_l[j];

    const f16* Ab = im48 + (size_t)gy * 2 * (MT * ND);   // 96 contiguous rows
    const f16* Bb = s16 + (size_t)gx * 2 * (NW * ND);    // 128 contiguous rows

    // staging offsets: A 3 issues, B 4 issues per thread (16 B each)
    int aoff[3], boff[4];
    #pragma unroll
    for (int q = 0; q < 3; ++q) {
        int f = q * 4096 + t * 16;
        int row = f >> 7, c = (f >> 4) & 7;
        aoff[q] = row * ND + (c ^ (row & 7)) * 8;
    }
    #pragma unroll
    for (int q = 0; q < 4; ++q) {
        int f = q * 4096 + t * 16;
        int row = f >> 7, c = (f >> 4) & 7;
        boff[q] = row * ND + (c ^ (row & 7)) * 8;
    }

    f32x4 acc[3][4];
    #pragma unroll
    for (int mi = 0; mi < 3; ++mi)
        #pragma unroll
        for (int nt = 0; nt < 4; ++nt)
            acc[mi][nt] = (f32x4){0.f, 0.f, 0.f, 0.f};

    for (int kk = 0; kk < ND; kk += 64) {
        #pragma unroll
        for (int q = 0; q < 3; ++q)
            gld_lds16(Ab + aoff[q] + kk, As + q * 4096 + t * 16);
        #pragma unroll
        for (int q = 0; q < 4; ++q)
            gld_lds16(Bb + boff[q] + kk, Bs + q * 4096 + t * 16);
        __syncthreads();
        #pragma unroll
        for (int ks = 0; ks < 2; ++ks) {
            f16x8 af[3], bf[4];
            #pragma unroll
            for (int mi = 0; mi < 3; ++mi) {
                int row = wi * 48 + mi * 16 + l16;
                int pc = (ks * 4 + quad) ^ (row & 7);
                af[mi] = *(const f16x8*)(As + row * 128 + pc * 16);
            }
            #pragma unroll
            for (int nt = 0; nt < 4; ++nt) {
                int row = wj * 64 + nt * 16 + l16;
                int pc = (ks * 4 + quad) ^ (row & 7);
                bf[nt] = *(const f16x8*)(Bs + row * 128 + pc * 16);
            }
            #pragma unroll
            for (int mi = 0; mi < 3; ++mi)
                #pragma unroll
                for (int nt = 0; nt < 4; ++nt)
                    acc[mi][nt] = __builtin_amdgcn_mfma_f32_16x16x32_f16(af[mi], bf[nt], acc[mi][nt], 0, 0, 0);
        }
        __syncthreads();
    }

    // ---- wave-private epilogue (verified R3/R5/R6 math) ----
    char* waveE = lds + wave * 8192;   // staging LDS is dead after final barrier
    {   // zero E^T rows 48..63 (chunks 6,7): pad/poison guard for quadform
        int col = lane;
        f16x8 z = {(f16)0.f,(f16)0.f,(f16)0.f,(f16)0.f,(f16)0.f,(f16)0.f,(f16)0.f,(f16)0.f};
        *(f16x8*)(waveE + col * 128 + ((6 ^ (col & 7)) * 16)) = z;
        *(f16x8*)(waveE + col * 128 + ((7 ^ (col & 7)) * 16)) = z;
    }

    // -- per-row l2-norm reciprocal (rows >= 36 -> 0) --
    float rn[3][4];
    #pragma unroll
    for (int mi = 0; mi < 3; ++mi) {
        #pragma unroll
        for (int r = 0; r < 4; ++r) {
            int row = mi * 16 + quad * 4 + r;
            float ss = 0.f;
            #pragma unroll
            for (int nt = 0; nt < 4; ++nt) {
                int col = nt * 16 + l16;
                float v = acc[mi][nt][r];
                float lv = v > 0.f ? v : 0.1f * v;
                if (col < L) ss += lv * lv;
            }
            ss += __shfl_xor(ss, 1, 64);
            ss += __shfl_xor(ss, 2, 64);
            ss += __shfl_xor(ss, 4, 64);
            ss += __shfl_xor(ss, 8, 64);
            rn[mi][r] = (row < NR) ? 1.0f / (sqrtf(ss) + EPSF) : 0.f;
        }
    }
    // -- e = exp(9*an): write E^T f16 (swizzled); cs/nu per-col partials --
    float cs[4] = {0.f, 0.f, 0.f, 0.f}, nu[4] = {0.f, 0.f, 0.f, 0.f};
    #pragma unroll
    for (int mi = 0; mi < 3; ++mi) {
        #pragma unroll
        for (int nt = 0; nt < 4; ++nt) {
            int col = nt * 16 + l16;
            f16x4 ew;
            #pragma unroll
            for (int r = 0; r < 4; ++r) {
                float v = acc[mi][nt][r];
                float lv = v > 0.f ? v : 0.1f * v;
                float e = expf(LAM_SM * ((col < L) ? lv * rn[mi][r] : 0.f));
                ew[r] = (f16)e;
                if (mi * 16 + quad * 4 + r < NR) { cs[nt] += e; nu[nt] += e * v; }
            }
            int c = mi * 2 + (quad >> 1);
            *(f16x4*)(waveE + col * 128 + ((c ^ (col & 7)) * 16) + (quad & 1) * 8) = ew;
        }
    }
    #pragma unroll
    for (int nt = 0; nt < 4; ++nt) {
        cs[nt] += __shfl_xor(cs[nt], 16, 64); cs[nt] += __shfl_xor(cs[nt], 32, 64);
        nu[nt] += __shfl_xor(nu[nt], 16, 64); nu[nt] += __shfl_xor(nu[nt], 32, 64);
    }
    // acc dead here -> pressure drops before quadform.

    // -- quadform mi-at-a-time: y = M[mi,:] x E^T; qf += e . y --
    const f16* Mi = Mg16 + (size_t)i * (MT * NW);
    float qf[4] = {0.f, 0.f, 0.f, 0.f};
    #pragma unroll
    for (int mi = 0; mi < 3; ++mi) {
        f32x4 y[4];
        #pragma unroll
        for (int nt = 0; nt < 4; ++nt) y[nt] = (f32x4){0.f, 0.f, 0.f, 0.f};
        #pragma unroll
        for (int ks = 0; ks < 2; ++ks) {
            f16x8 aq = *(const f16x8*)(Mi + (mi * 16 + l16) * NW + ks * 32 + quad * 8);
            #pragma unroll
            for (int nt = 0; nt < 4; ++nt) {
                int col = nt * 16 + l16;
                int pch = (ks * 4 + quad) ^ (col & 7);
                f16x8 bq = *(const f16x8*)(waveE + col * 128 + pch * 16);
                y[nt] = __builtin_amdgcn_mfma_f32_16x16x32_f16(aq, bq, y[nt], 0, 0, 0);
            }
        }
        int row0 = mi * 16 + quad * 4;
        int c = row0 >> 3, sub = (row0 >> 2) & 1;
        #pragma unroll
        for (int nt = 0; nt < 4; ++nt) {
            int col = nt * 16 + l16;
            f16x4 ev = *(const f16x4*)(waveE + col * 128 + ((c ^ (col & 7)) * 16) + sub * 8);
            #pragma unroll
            for (int r = 0; r < 4; ++r) qf[nt] += y[nt][r] * (float)ev[r];
        }
    }
    #pragma unroll
    for (int nt = 0; nt < 4; ++nt) {
        qf[nt] += __shfl_xor(qf[nt], 16, 64); qf[nt] += __shfl_xor(qf[nt], 32, 64);
    }
    // -- finalize: cosine row values, LSE over words, write score --
    float lse = 0.f;
    #pragma unroll
    for (int nt = 0; nt < 4; ++nt) {
        int col = nt * 16 + l16;
        float num  = nu[nt] / cs[nt];
        float nwei = sqrtf(fmaxf(qf[nt], 0.f)) / cs[nt];
        float nc   = ncap[j * NW + col];
        float rowv = num / fmaxf(nc * nwei, EPSF);
        lse += (col < L) ? expf(LAM_LSE * rowv) : 0.f;
    }
    lse += __shfl_xor(lse, 1, 64);
    lse += __shfl_xor(lse, 2, 64);
    lse += __shfl_xor(lse, 4, 64);
    lse += __shfl_xor(lse, 8, 64);
    if (lane == 0) scores[i * NB + j] = logf(lse) / LAM_LSE;
}

// ---------------- kernel C: contrastive loss reduction ----------------
__global__ __launch_bounds__(128) void loss_kernel(const float* __restrict__ S,
                                                   float* __restrict__ out) {
    __shared__ float part[NB];
    int t = threadIdx.x;
    float dii = S[t * NB + t];
    float rmax = 0.f, cmax = 0.f;
    for (int k = 0; k < NB; ++k) {
        if (k != t) {
            float vs = MARGINF + S[t * NB + k] - dii;
            rmax = fmaxf(rmax, fmaxf(vs, 0.f));
            float vi = MARGINF + S[k * NB + t] - dii;
            cmax = fmaxf(cmax, fmaxf(vi, 0.f));
        }
    }
    part[t] = rmax + cmax;
    __syncthreads();
    if (t == 0) {
        float sum = 0.f;
        for (int k = 0; k < NB; ++k) sum += part[k];
        out[0] = sum;
    }
}

extern "C" void kernel_launch(void* const* d_in, const int* in_sizes, int n_in,
                              void* d_out, int out_size, void* d_ws, size_t ws_size,
                              hipStream_t stream) {
    const float* im  = (const float*)d_in[0];
    const float* s   = (const float*)d_in[1];
    const int*   s_l = (const int*)d_in[2];

    float* scores = (float*)d_ws;                          // 16384 f32
    float* ncap   = scores + NB * NB;                      // 8192 f32
    f16*   Mg16   = (f16*)(ncap + NB * NW);                // 128*48*64
    f16*   im48   = Mg16 + (size_t)NB * MT * NW;           // 128*48*1024
    f16*   s16    = im48 + (size_t)NB * MT * ND;           // 128*64*1024

    dim3 cgrid(NB, MT + NW);
    convert_kernel<<<cgrid, 256, 0, stream>>>(im, s, im48, s16, ncap);
    dim3 ggrid(NB, 3);
    gram16_kernel<<<ggrid, 256, 0, stream>>>(im48, Mg16);
    fused_pair_kernel<<<4096, 256, 0, stream>>>(im48, s16, s_l, Mg16, ncap, scores);
    loss_kernel<<<1, NB, 0, stream>>>(scores, (float*)d_out);
}

// Round 8
// 287.918 us; speedup vs baseline: 1.1046x; 1.1046x over previous
//
#include <hip/hip_runtime.h>
#include <hip/hip_bf16.h>
#include <math.h>
#include <stdint.h>

#define NB 128     // batch (images and captions)
#define NR 36      // regions
#define NW 64      // words
#define ND 1024    // dim
#define MT 48      // NR padded to 3 MFMA m-tiles
#define EPSF 1e-8f
#define LAM_SM 9.0f
#define LAM_LSE 6.0f
#define MARGINF 0.2f

typedef _Float16 f16;
typedef f16 f16x4 __attribute__((ext_vector_type(4)));
typedef f16 f16x8 __attribute__((ext_vector_type(8)));
typedef float f32x4 __attribute__((ext_vector_type(4)));

__device__ __forceinline__ void gld_lds16(const void* g, void* l) {
    __builtin_amdgcn_global_load_lds(
        (const __attribute__((address_space(1))) uint32_t*)(uintptr_t)g,
        (__attribute__((address_space(3))) uint32_t*)(uint32_t)(uintptr_t)l,
        16, 0, 0);
}

// ---------------- kernel 0: fp32 -> f16 (im zero-padded to 48 rows) + ncap --------
__global__ __launch_bounds__(256) void convert_kernel(
    const float* __restrict__ im, const float* __restrict__ s,
    f16* __restrict__ im48, f16* __restrict__ s16, float* __restrict__ ncap) {
    __shared__ float wsum[4];
    const int b = blockIdx.x, row = blockIdx.y, t = threadIdx.x;
    if (row < MT) {
        f16x4* dst = (f16x4*)(im48 + ((size_t)b * MT + row) * ND);
        if (row < NR) {
            const float4* src = (const float4*)(im + ((size_t)b * NR + row) * ND);
            float4 v = src[t];
            f16x4 h = {(f16)v.x, (f16)v.y, (f16)v.z, (f16)v.w};
            dst[t] = h;
        } else {
            dst[t] = (f16x4){(f16)0.f, (f16)0.f, (f16)0.f, (f16)0.f};
        }
    } else {
        const int w = row - MT;
        const float4* src = (const float4*)(s + ((size_t)b * NW + w) * ND);
        float4 v = src[t];
        f16x4 h = {(f16)v.x, (f16)v.y, (f16)v.z, (f16)v.w};
        ((f16x4*)(s16 + ((size_t)b * NW + w) * ND))[t] = h;
        float ss = v.x * v.x + v.y * v.y + v.z * v.z + v.w * v.w;
        #pragma unroll
        for (int off = 1; off < 64; off <<= 1) ss += __shfl_xor(ss, off, 64);
        if ((t & 63) == 0) wsum[t >> 6] = ss;
        __syncthreads();
        if (t == 0) ncap[b * NW + w] = sqrtf(wsum[0] + wsum[1] + wsum[2] + wsum[3]);
    }
}

// ---------------- kernel A: per-image f16 Gram [48][64] via MFMA ------------------
__global__ __launch_bounds__(256) void gram16_kernel(
    const f16* __restrict__ im48, f16* __restrict__ Mg16) {
    const int b = blockIdx.x, mt = blockIdx.y;          // mt 0..2
    const int wave = threadIdx.x >> 6, lane = threadIdx.x & 63;
    const int quad = lane >> 4, l16 = lane & 15;
    const int nt = wave;                                 // n-tile 0..3
    const f16* Ab = im48 + (size_t)b * (MT * ND);
    f32x4 acc = (f32x4){0.f, 0.f, 0.f, 0.f};
    for (int kk = 0; kk < ND; kk += 32) {
        f16x8 af = *(const f16x8*)(Ab + (mt * 16 + l16) * ND + kk + quad * 8);
        f16x8 bf = *(const f16x8*)(Ab + (nt * 16 + l16) * ND + kk + quad * 8);
        acc = __builtin_amdgcn_mfma_f32_16x16x32_f16(af, bf, acc, 0, 0, 0);
    }
    f16* Mb = Mg16 + (size_t)b * (MT * NW);
    #pragma unroll
    for (int r = 0; r < 4; ++r) {
        int row = mt * 16 + quad * 4 + r;
        Mb[row * NW + nt * 16 + l16] = (f16)acc[r];
    }
}

// ---------------- kernel B: fused GEMM + epilogue -----------------------------
// Block tile 96x128 = 2 images x 2 captions; wave = one pair (acc[3][4]).
// R8: gx-fast mapping (XCD ~ lin%8 owns gx%8 -> 2.1MB B L2-resident; per-gy
// A-tile reused by the XCD's 8 consecutive blocks). A pad rows (36-47, 84-95)
// pre-zeroed once, DMA predicated off -> 25% less A fetch.
#define A_LDS 12288   // 96 rows x 128 B
__global__ __launch_bounds__(256) void fused_pair_kernel(
    const f16* __restrict__ im48, const f16* __restrict__ s16,
    const int* __restrict__ s_l, const f16* __restrict__ Mg16,
    const float* __restrict__ ncap, float* __restrict__ scores) {
    __shared__ __align__(16) char lds[32768];
    char* As = lds;              // [96][128B]
    char* Bs = lds + A_LDS;      // [128][128B]
    const int t = threadIdx.x;
    const int wave = t >> 6, lane = t & 63;
    const int quad = lane >> 4, l16 = lane & 15;
    const int wi = wave >> 1, wj = wave & 1;

    // gx fast: XCD (~lin%8) sees gx = x, x+8, ... -> B slice L2-resident;
    // gy slow: all XCDs sweep the same A-tile window concurrently (L3-hot).
    const int lin = blockIdx.x;            // 0..4095
    const int gx = lin & 63, gy = lin >> 6;
    const int i = gy * 2 + wi;             // this wave's image
    const int j = gx * 2 + wj;             // this wave's caption
    const int L = s_l[j];

    const f16* Ab = im48 + (size_t)gy * 2 * (MT * ND);   // 96 contiguous rows
    const f16* Bb = s16 + (size_t)gx * 2 * (NW * ND);    // 128 contiguous rows

    // staging offsets: A 3 issues (pad rows predicated off), B 4 issues
    int aoff[3], boff[4];
    bool aact[3];
    #pragma unroll
    for (int q = 0; q < 3; ++q) {
        int f = q * 4096 + t * 16;
        int row = f >> 7, c = (f >> 4) & 7;
        aoff[q] = row * ND + (c ^ (row & 7)) * 8;
        aact[q] = (row % MT) < NR;         // rows 36-47 / 84-95 are zero pad
    }
    #pragma unroll
    for (int q = 0; q < 4; ++q) {
        int f = q * 4096 + t * 16;
        int row = f >> 7, c = (f >> 4) & 7;
        boff[q] = row * ND + (c ^ (row & 7)) * 8;
    }

    // pre-zero the 24 pad rows of As (never DMA'd)
    if (t < 192) {
        int r = (t < 96) ? (36 + (t >> 3)) : (84 + ((t - 96) >> 3));
        *(float4*)(As + r * 128 + (t & 7) * 16) = make_float4(0.f, 0.f, 0.f, 0.f);
    }

    f32x4 acc[3][4];
    #pragma unroll
    for (int mi = 0; mi < 3; ++mi)
        #pragma unroll
        for (int nt = 0; nt < 4; ++nt)
            acc[mi][nt] = (f32x4){0.f, 0.f, 0.f, 0.f};

    for (int kk = 0; kk < ND; kk += 64) {
        #pragma unroll
        for (int q = 0; q < 3; ++q)
            if (aact[q]) gld_lds16(Ab + aoff[q] + kk, As + q * 4096 + t * 16);
        #pragma unroll
        for (int q = 0; q < 4; ++q)
            gld_lds16(Bb + boff[q] + kk, Bs + q * 4096 + t * 16);
        __syncthreads();
        #pragma unroll
        for (int ks = 0; ks < 2; ++ks) {
            f16x8 af[3], bf[4];
            #pragma unroll
            for (int mi = 0; mi < 3; ++mi) {
                int row = wi * 48 + mi * 16 + l16;
                int pc = (ks * 4 + quad) ^ (row & 7);
                af[mi] = *(const f16x8*)(As + row * 128 + pc * 16);
            }
            #pragma unroll
            for (int nt = 0; nt < 4; ++nt) {
                int row = wj * 64 + nt * 16 + l16;
                int pc = (ks * 4 + quad) ^ (row & 7);
                bf[nt] = *(const f16x8*)(Bs + row * 128 + pc * 16);
            }
            #pragma unroll
            for (int mi = 0; mi < 3; ++mi)
                #pragma unroll
                for (int nt = 0; nt < 4; ++nt)
                    acc[mi][nt] = __builtin_amdgcn_mfma_f32_16x16x32_f16(af[mi], bf[nt], acc[mi][nt], 0, 0, 0);
        }
        __syncthreads();
    }

    // ---- wave-private epilogue (verified R3/R5/R6/R7 math) ----
    char* waveE = lds + wave * 8192;   // staging LDS dead after final barrier
    {   // zero E^T rows 48..63 (chunks 6,7): pad/poison guard for quadform
        int col = lane;
        f16x8 z = {(f16)0.f,(f16)0.f,(f16)0.f,(f16)0.f,(f16)0.f,(f16)0.f,(f16)0.f,(f16)0.f};
        *(f16x8*)(waveE + col * 128 + ((6 ^ (col & 7)) * 16)) = z;
        *(f16x8*)(waveE + col * 128 + ((7 ^ (col & 7)) * 16)) = z;
    }

    // -- per-row l2-norm reciprocal (rows >= 36 -> 0) --
    float rn[3][4];
    #pragma unroll
    for (int mi = 0; mi < 3; ++mi) {
        #pragma unroll
        for (int r = 0; r < 4; ++r) {
            int row = mi * 16 + quad * 4 + r;
            float ss = 0.f;
            #pragma unroll
            for (int nt = 0; nt < 4; ++nt) {
                int col = nt * 16 + l16;
                float v = acc[mi][nt][r];
                float lv = v > 0.f ? v : 0.1f * v;
                if (col < L) ss += lv * lv;
            }
            ss += __shfl_xor(ss, 1, 64);
            ss += __shfl_xor(ss, 2, 64);
            ss += __shfl_xor(ss, 4, 64);
            ss += __shfl_xor(ss, 8, 64);
            rn[mi][r] = (row < NR) ? 1.0f / (sqrtf(ss) + EPSF) : 0.f;
        }
    }
    // -- e = exp(9*an): write E^T f16 (swizzled); cs/nu per-col partials --
    float cs[4] = {0.f, 0.f, 0.f, 0.f}, nu[4] = {0.f, 0.f, 0.f, 0.f};
    #pragma unroll
    for (int mi = 0; mi < 3; ++mi) {
        #pragma unroll
        for (int nt = 0; nt < 4; ++nt) {
            int col = nt * 16 + l16;
            f16x4 ew;
            #pragma unroll
            for (int r = 0; r < 4; ++r) {
                float v = acc[mi][nt][r];
                float lv = v > 0.f ? v : 0.1f * v;
                float e = __expf(LAM_SM * ((col < L) ? lv * rn[mi][r] : 0.f));
                ew[r] = (f16)e;
                if (mi * 16 + quad * 4 + r < NR) { cs[nt] += e; nu[nt] += e * v; }
            }
            int c = mi * 2 + (quad >> 1);
            *(f16x4*)(waveE + col * 128 + ((c ^ (col & 7)) * 16) + (quad & 1) * 8) = ew;
        }
    }
    #pragma unroll
    for (int nt = 0; nt < 4; ++nt) {
        cs[nt] += __shfl_xor(cs[nt], 16, 64); cs[nt] += __shfl_xor(cs[nt], 32, 64);
        nu[nt] += __shfl_xor(nu[nt], 16, 64); nu[nt] += __shfl_xor(nu[nt], 32, 64);
    }
    // acc dead here -> pressure drops before quadform.

    // -- quadform mi-at-a-time: y = M[mi,:] x E^T; qf += e . y --
    const f16* Mi = Mg16 + (size_t)i * (MT * NW);
    float qf[4] = {0.f, 0.f, 0.f, 0.f};
    #pragma unroll
    for (int mi = 0; mi < 3; ++mi) {
        f32x4 y[4];
        #pragma unroll
        for (int nt = 0; nt < 4; ++nt) y[nt] = (f32x4){0.f, 0.f, 0.f, 0.f};
        #pragma unroll
        for (int ks = 0; ks < 2; ++ks) {
            f16x8 aq = *(const f16x8*)(Mi + (mi * 16 + l16) * NW + ks * 32 + quad * 8);
            #pragma unroll
            for (int nt = 0; nt < 4; ++nt) {
                int col = nt * 16 + l16;
                int pch = (ks * 4 + quad) ^ (col & 7);
                f16x8 bq = *(const f16x8*)(waveE + col * 128 + pch * 16);
                y[nt] = __builtin_amdgcn_mfma_f32_16x16x32_f16(aq, bq, y[nt], 0, 0, 0);
            }
        }
        int row0 = mi * 16 + quad * 4;
        int c = row0 >> 3, sub = (row0 >> 2) & 1;
        #pragma unroll
        for (int nt = 0; nt < 4; ++nt) {
            int col = nt * 16 + l16;
            f16x4 ev = *(const f16x4*)(waveE + col * 128 + ((c ^ (col & 7)) * 16) + sub * 8);
            #pragma unroll
            for (int r = 0; r < 4; ++r) qf[nt] += y[nt][r] * (float)ev[r];
        }
    }
    #pragma unroll
    for (int nt = 0; nt < 4; ++nt) {
        qf[nt] += __shfl_xor(qf[nt], 16, 64); qf[nt] += __shfl_xor(qf[nt], 32, 64);
    }
    // -- finalize: cosine row values, LSE over words, write score --
    float lse = 0.f;
    #pragma unroll
    for (int nt = 0; nt < 4; ++nt) {
        int col = nt * 16 + l16;
        float num  = nu[nt] / cs[nt];
        float nwei = sqrtf(fmaxf(qf[nt], 0.f)) / cs[nt];
        float nc   = ncap[j * NW + col];
        float rowv = num / fmaxf(nc * nwei, EPSF);
        lse += (col < L) ? __expf(LAM_LSE * rowv) : 0.f;
    }
    lse += __shfl_xor(lse, 1, 64);
    lse += __shfl_xor(lse, 2, 64);
    lse += __shfl_xor(lse, 4, 64);
    lse += __shfl_xor(lse, 8, 64);
    if (lane == 0) scores[i * NB + j] = __logf(lse) / LAM_LSE;
}

// ---------------- kernel C: contrastive loss reduction ----------------
__global__ __launch_bounds__(128) void loss_kernel(const float* __restrict__ S,
                                                   float* __restrict__ out) {
    __shared__ float part[NB];
    int t = threadIdx.x;
    float dii = S[t * NB + t];
    float rmax = 0.f, cmax = 0.f;
    for (int k = 0; k < NB; ++k) {
        if (k != t) {
            float vs = MARGINF + S[t * NB + k] - dii;
            rmax = fmaxf(rmax, fmaxf(vs, 0.f));
            float vi = MARGINF + S[k * NB + t] - dii;
            cmax = fmaxf(cmax, fmaxf(vi, 0.f));
        }
    }
    part[t] = rmax + cmax;
    __syncthreads();
    if (t == 0) {
        float sum = 0.f;
        for (int k = 0; k < NB; ++k) sum += part[k];
        out[0] = sum;
    }
}

extern "C" void kernel_launch(void* const* d_in, const int* in_sizes, int n_in,
                              void* d_out, int out_size, void* d_ws, size_t ws_size,
                              hipStream_t stream) {
    const float* im  = (const float*)d_in[0];
    const float* s   = (const float*)d_in[1];
    const int*   s_l = (const int*)d_in[2];

    float* scores = (float*)d_ws;                          // 16384 f32
    float* ncap   = scores + NB * NB;                      // 8192 f32
    f16*   Mg16   = (f16*)(ncap + NB * NW);                // 128*48*64
    f16*   im48   = Mg16 + (size_t)NB * MT * NW;           // 128*48*1024
    f16*   s16    = im48 + (size_t)NB * MT * ND;           // 128*64*1024

    dim3 cgrid(NB, MT + NW);
    convert_kernel<<<cgrid, 256, 0, stream>>>(im, s, im48, s16, ncap);
    dim3 ggrid(NB, 3);
    gram16_kernel<<<ggrid, 256, 0, stream>>>(im48, Mg16);
    fused_pair_kernel<<<4096, 256, 0, stream>>>(im48, s16, s_l, Mg16, ncap, scores);
    loss_kernel<<<1, NB, 0, stream>>>(scores, (float*)d_out);
}